// Round 1
// 3010.387 us; speedup vs baseline: 1.3156x; 1.3156x over previous
//
#include <hip/hip_runtime.h>
#include <math.h>
#include <limits.h>

#define H 128
#define V 32000
#define CD 256
#define T_STEPS 21
#define NS 5
#define SOS 1
#define EOS 2
#define B 1024          // unique rows; reference B=5120 is 5 identical copies of each
#define BFULL 5120
#define NCHUNK 250      // V / 128

typedef _Float16 f16;
typedef f16   half8   __attribute__((ext_vector_type(8)));
typedef float floatx4 __attribute__((ext_vector_type(4)));

__device__ __forceinline__ float bf2f(unsigned short u) {
    return __uint_as_float(((unsigned)u) << 16);
}

// np-faithful f32 sigmoid/tanh: f64 interior, single f32 round per np op.
__device__ __forceinline__ float sig32(float x) {
    float t = (float)exp(-(double)x);
    float r = __fadd_rn(1.0f, t);
    return __fdiv_rn(1.0f, r);
}
__device__ __forceinline__ float tanh32(float x) { return (float)tanh((double)x); }

// ---------------------------------------------------------------- input dtype sniffer
__global__ void k_detect(const unsigned short* __restrict__ e, int* __restrict__ flag) {
    int i = threadIdx.x;
    unsigned short u = e[2 * i];
    int ex = (u >> 7) & 0xFF;
    bool wild = ((u & 0x7FFF) != 0) && (ex < 0x60 || ex > 0x8F);
    unsigned long long m = __ballot(wild);
    if (i == 0) *flag = (m != 0ull) ? 1 : 0;   // 1 = f32 inputs, 0 = bf16
}

// ---------------------------------------------------------------- transcode input -> f32
__global__ void k_transcode(const void* __restrict__ src, float* __restrict__ dst,
                            int n, const int* __restrict__ flag) {
    int i = blockIdx.x * blockDim.x + threadIdx.x;
    if (i >= n) return;
    if (*flag) dst[i] = ((const float*)src)[i];
    else       dst[i] = bf2f(((const unsigned short*)src)[i]);
}

// ---------------------------------------------------------------- W2: per-row norm + scaled f16 hi/lo split (once per launch)
// W' = w*256 (exact); hi = f16(W'); lo = f16(W' - hi). hi+lo represents w*256
// to ~2^-22 relative; 256 scaling keeps lo out of f16-subnormal range for all
// |w| > 2e-6, so MFMA denorm-flush behavior is immaterial.
__global__ __launch_bounds__(256) void k_wsplit(
    const void* __restrict__ W2_raw, unsigned short* __restrict__ wh,
    unsigned short* __restrict__ wl, float* __restrict__ wn,
    const int* __restrict__ flag) {
    int v = blockIdx.x * blockDim.x + threadIdx.x;
    if (v >= V) return;
    const bool isf = (*flag != 0);
    f16* whp = (f16*)wh;
    f16* wlp = (f16*)wl;
    float s = 0.f;
    for (int k = 0; k < H; ++k) {
        float wv;
        if (isf) wv = ((const float*)W2_raw)[(long)v * H + k];
        else     wv = bf2f(((const unsigned short*)W2_raw)[(long)v * H + k]);
        s += wv * wv;
        float ws = wv * 256.0f;
        f16 hh = (f16)ws;
        f16 ll = (f16)(ws - (float)hh);
        whp[(long)v * H + k] = hh;
        wlp[(long)v * H + k] = ll;
    }
    wn[v] = sqrtf(s);
}

// ---------------------------------------------------------------- global max ||w|| (once per launch)
__global__ __launch_bounds__(256) void k_wmax(const float* __restrict__ wn, float* __restrict__ wmax) {
    __shared__ float red[4];
    int tid = threadIdx.x;
    float m = 0.f;
    for (int i = tid; i < V; i += 256) m = fmaxf(m, wn[i]);
    #pragma unroll
    for (int off = 1; off < 64; off <<= 1) m = fmaxf(m, __shfl_xor(m, off, 64));
    if ((tid & 63) == 0) red[tid >> 6] = m;
    __syncthreads();
    if (tid == 0) *wmax = fmaxf(fmaxf(red[0], red[1]), fmaxf(red[2], red[3]));
}

// ---------------------------------------------------------------- init it/unf
__global__ void k_init_state(int* __restrict__ it, int* __restrict__ unf) {
    int i = blockIdx.x * blockDim.x + threadIdx.x;
    if (i < B) { it[i] = SOS; unf[i] = 1; }
}

// ---------------------------------------------------------------- hc = fl32(x @ W_fc.T) + b_fc
__global__ __launch_bounds__(256) void k_init_hc(
    const float* __restrict__ xf, const float* __restrict__ Wfc,
    const float* __restrict__ bfc, float* __restrict__ h, float* __restrict__ c) {
    __shared__ float xl[CD];
    int r = blockIdx.x;
    int j = threadIdx.x;
    xl[j] = xf[(long)r * CD + j];
    __syncthreads();
    const float4* w4 = (const float4*)(Wfc + (long)j * CD);
    double acc = 0.0;
    for (int k4 = 0; k4 < CD / 4; ++k4) {
        float4 w = w4[k4];
        int k = k4 * 4;
        acc += (double)xl[k]     * (double)w.x;
        acc += (double)xl[k + 1] * (double)w.y;
        acc += (double)xl[k + 2] * (double)w.z;
        acc += (double)xl[k + 3] * (double)w.w;
    }
    float hc = __fadd_rn((float)acc, bfc[j]);
    if (j < H) h[(long)r * H + j] = hc;
    else       c[(long)r * H + (j - H)] = hc;
}

// ---------------------------------------------------------------- gates (f32 np-faithful) — unchanged
__global__ __launch_bounds__(256) void k_gates(
    const void* __restrict__ embed_raw, const float* __restrict__ h,
    const float* __restrict__ Wih, const float* __restrict__ Whh,
    const float* __restrict__ bih, const float* __restrict__ bhh,
    const int* __restrict__ it, float* __restrict__ gates,
    const int* __restrict__ flag) {
    __shared__ float At[16][68];
    __shared__ float Wt[16][68];
    const bool isf = (*flag != 0);
    int tid = threadIdx.x;
    int tx = tid & 15, ty = tid >> 4;
    int rb = blockIdx.x * 64, gb = blockIdx.y * 64;
    int lr = tid >> 2;
    int lq = (tid & 3) * 4;
    int arow = rb + lr;
    int grow = gb + lr;
    int tok = it[arow];
    const float*          erow_f = (const float*)embed_raw + (long)tok * H;
    const unsigned short* erow_h = (const unsigned short*)embed_raw + (long)tok * H;
    const float* hrow = h + (long)arow * H;
    const float* wi   = Wih + (long)grow * H;
    const float* wh   = Whh + (long)grow * H;
    double acc1[4][4] = {};
    double acc2[4][4] = {};
    for (int k0 = 0; k0 < 2 * H; k0 += 16) {
        int k = k0 + lq;
        float v0, v1, v2, v3;
        if (k < H) {
            if (isf) {
                float4 f = *(const float4*)(erow_f + k);
                v0 = f.x; v1 = f.y; v2 = f.z; v3 = f.w;
            } else {
                ushort4 u = *(const ushort4*)(erow_h + k);
                v0 = bf2f(u.x); v1 = bf2f(u.y); v2 = bf2f(u.z); v3 = bf2f(u.w);
            }
        } else {
            float4 f = *(const float4*)(hrow + (k - H));
            v0 = f.x; v1 = f.y; v2 = f.z; v3 = f.w;
        }
        At[lq + 0][lr] = v0; At[lq + 1][lr] = v1; At[lq + 2][lr] = v2; At[lq + 3][lr] = v3;
        float4 g;
        if (k < H) g = *(const float4*)(wi + k);
        else       g = *(const float4*)(wh + (k - H));
        Wt[lq + 0][lr] = g.x; Wt[lq + 1][lr] = g.y; Wt[lq + 2][lr] = g.z; Wt[lq + 3][lr] = g.w;
        __syncthreads();
        if (k0 < H) {
            #pragma unroll
            for (int kk = 0; kk < 16; ++kk) {
                float a[4], w[4];
                #pragma unroll
                for (int i = 0; i < 4; ++i) a[i] = At[kk][ty * 4 + i];
                #pragma unroll
                for (int j = 0; j < 4; ++j) w[j] = Wt[kk][tx * 4 + j];
                #pragma unroll
                for (int i = 0; i < 4; ++i)
                    #pragma unroll
                    for (int j = 0; j < 4; ++j)
                        acc1[i][j] += (double)a[i] * (double)w[j];
            }
        } else {
            #pragma unroll
            for (int kk = 0; kk < 16; ++kk) {
                float a[4], w[4];
                #pragma unroll
                for (int i = 0; i < 4; ++i) a[i] = At[kk][ty * 4 + i];
                #pragma unroll
                for (int j = 0; j < 4; ++j) w[j] = Wt[kk][tx * 4 + j];
                #pragma unroll
                for (int i = 0; i < 4; ++i)
                    #pragma unroll
                    for (int j = 0; j < 4; ++j)
                        acc2[i][j] += (double)a[i] * (double)w[j];
            }
        }
        __syncthreads();
    }
    #pragma unroll
    for (int i = 0; i < 4; ++i) {
        long row = rb + ty * 4 + i;
        #pragma unroll
        for (int j = 0; j < 4; ++j) {
            int g = gb + tx * 4 + j;
            float t = __fadd_rn((float)acc1[i][j], bih[g]);
            t = __fadd_rn(t, (float)acc2[i][j]);
            t = __fadd_rn(t, bhh[g]);
            gates[row * (4 * H) + g] = t;
        }
    }
}

// ---------------------------------------------------------------- LSTM cell + p-projection (+ scaled f16 hi/lo split of p)
__global__ __launch_bounds__(256) void k_cell_proj(
    const float* __restrict__ gates, float* __restrict__ h, float* __restrict__ c,
    const float* __restrict__ W1, const float* __restrict__ b1,
    float* __restrict__ p32, unsigned short* __restrict__ ph,
    unsigned short* __restrict__ pl) {
    __shared__ float hl[8][132];
    int tid = threadIdx.x;
    int rb = blockIdx.x * 8;
    #pragma unroll
    for (int i = 0; i < 4; ++i) {
        int lin = tid + i * 256;
        int lr = lin >> 7, j = lin & 127;
        long row = rb + lr;
        const float* g = gates + row * 512;
        float gi = g[j], gf = g[j + 128], gg = g[j + 256], go = g[j + 384];
        float cv = c[row * 128 + j];
        float si = sig32(gi);
        float sf = sig32(gf);
        float so = sig32(go);
        float tg = tanh32(gg);
        float cn = __fadd_rn(__fmul_rn(sf, cv), __fmul_rn(si, tg));
        float hn = __fmul_rn(so, tanh32(cn));
        c[row * 128 + j] = cn;
        h[row * 128 + j] = hn;
        hl[lr][j] = hn;
    }
    __syncthreads();
    int j = tid & 127;
    int rbase = (tid >> 7) * 4;
    const float4* w4 = (const float4*)(W1 + (long)j * H);
    double acc[4] = {};
    for (int k4 = 0; k4 < H / 4; ++k4) {
        float4 w = w4[k4];
        int k = k4 * 4;
        #pragma unroll
        for (int rr = 0; rr < 4; ++rr) {
            acc[rr] += (double)hl[rbase + rr][k]     * (double)w.x;
            acc[rr] += (double)hl[rbase + rr][k + 1] * (double)w.y;
            acc[rr] += (double)hl[rbase + rr][k + 2] * (double)w.z;
            acc[rr] += (double)hl[rbase + rr][k + 3] * (double)w.w;
        }
    }
    #pragma unroll
    for (int rr = 0; rr < 4; ++rr) {
        long row = rb + rbase + rr;
        float pv = __fadd_rn((float)acc[rr], b1[j]);
        p32[row * H + j] = pv;
        float ps = pv * 256.0f;
        f16 hh = (f16)ps;
        f16 ll = (f16)(ps - (float)hh);
        ((f16*)ph)[row * H + j] = hh;
        ((f16*)pl)[row * H + j] = ll;
    }
}

// ---------------------------------------------------------------- vocab scan via split-f16 MFMA (approx, rigorously bounded):
// logit = 2^-16 * (p_hi.W_hi + p_hi.W_lo + p_lo.W_hi) + b2, f32 MFMA accum.
// |approx - f64 recipe| <= ~2.5e-5*||p||*||w|| (covered by widened eps in
// k_final, which restores exactness of the argmax/token path via f64 rescue).
// 256 rows x 128 cols per block, 4 waves, each wave 4x8 16x16 tiles,
// register-only (no LDS, no barriers), operands straight from L2.
__global__ __launch_bounds__(256, 2) void k_vscan_mfma(
    const unsigned short* __restrict__ ph_, const unsigned short* __restrict__ pl_,
    const unsigned short* __restrict__ wh_, const unsigned short* __restrict__ wl_,
    const float* __restrict__ b2, float* __restrict__ cm, float* __restrict__ cs) {
    const f16* ph = (const f16*)ph_;
    const f16* pl = (const f16*)pl_;
    const f16* wh = (const f16*)wh_;
    const f16* wl = (const f16*)wl_;
    int tid  = threadIdx.x;
    int lane = tid & 63, wid = tid >> 6;
    int tx = lane & 15, kg = lane >> 4;
    int rbw = blockIdx.x * 256 + wid * 64;
    int cb  = blockIdx.y;
    int vb  = cb * 128;

    floatx4 acc[4][8];
    #pragma unroll
    for (int m = 0; m < 4; ++m)
        #pragma unroll
        for (int n = 0; n < 8; ++n)
            acc[m][n] = (floatx4){0.f, 0.f, 0.f, 0.f};

    int aoffs[4], boffs[8];
    #pragma unroll
    for (int m = 0; m < 4; ++m) aoffs[m] = (rbw + m * 16 + tx) * H + kg * 8;
    #pragma unroll
    for (int n = 0; n < 8; ++n) boffs[n] = (vb + n * 16 + tx) * H + kg * 8;

    #pragma unroll
    for (int kk = 0; kk < 4; ++kk) {
        half8 Ah[4], Al[4];
        #pragma unroll
        for (int m = 0; m < 4; ++m) {
            Ah[m] = *(const half8*)(ph + aoffs[m] + kk * 32);
            Al[m] = *(const half8*)(pl + aoffs[m] + kk * 32);
        }
        #pragma unroll
        for (int n = 0; n < 8; ++n) {
            half8 Bh = *(const half8*)(wh + boffs[n] + kk * 32);
            half8 Bl = *(const half8*)(wl + boffs[n] + kk * 32);
            #pragma unroll
            for (int m = 0; m < 4; ++m)
                acc[m][n] = __builtin_amdgcn_mfma_f32_16x16x32_f16(Ah[m], Bh, acc[m][n], 0, 0, 0);
            #pragma unroll
            for (int m = 0; m < 4; ++m)
                acc[m][n] = __builtin_amdgcn_mfma_f32_16x16x32_f16(Ah[m], Bl, acc[m][n], 0, 0, 0);
            #pragma unroll
            for (int m = 0; m < 4; ++m)
                acc[m][n] = __builtin_amdgcn_mfma_f32_16x16x32_f16(Al[m], Bh, acc[m][n], 0, 0, 0);
        }
    }

    // epilogue: descale (exact 2^-16), bias, per-(row,chunk) max + expf-sum.
    // C/D layout: col = lane&15 (tx), row = kg*4 + reg.
    const float S2 = 1.0f / 65536.0f;
    float bb[8];
    #pragma unroll
    for (int n = 0; n < 8; ++n) bb[n] = b2[vb + n * 16 + tx];
    #pragma unroll
    for (int m = 0; m < 4; ++m) {
        #pragma unroll
        for (int r = 0; r < 4; ++r) {
            float mxr = -__builtin_inff();
            float sr = 0.f;
            #pragma unroll
            for (int n = 0; n < 8; ++n) {
                float l = acc[m][n][r] * S2 + bb[n];
                mxr = fmaxf(mxr, l);
                sr += __expf(l);
            }
            #pragma unroll
            for (int off = 1; off < 16; off <<= 1) {
                mxr = fmaxf(mxr, __shfl_xor(mxr, off, 64));
                sr += __shfl_xor(sr, off, 64);
            }
            if (tx == 0) {
                long row = rbw + m * 16 + kg * 4 + r;
                cm[row * NCHUNK + cb] = mxr;
                cs[row * NCHUNK + cb] = sr;
            }
        }
    }
}

// ---------------------------------------------------------------- finalize: norm-bounded candidate set, exact f64 rescue
__global__ __launch_bounds__(64) void k_final(
    const float* __restrict__ cm, const float* __restrict__ cs,
    const float* __restrict__ p32, const void* __restrict__ W2_raw,
    const float* __restrict__ b2, const float* __restrict__ wmax,
    int* __restrict__ it, int* __restrict__ unf,
    float* __restrict__ out, int t, const int* __restrict__ flag) {
    const bool isf = (*flag != 0);
    int r = blockIdx.x;
    int lane = threadIdx.x;
    const float* cmr = cm + (long)r * NCHUNK;
    const float* csr = cs + (long)r * NCHUNK;
    const float* pr = p32 + (long)r * H;

    // ||p||
    float pa = pr[lane], pb = pr[lane + 64];
    float pn2 = pa * pa + pb * pb;
    #pragma unroll
    for (int off = 1; off < 64; off <<= 1) pn2 += __shfl_xor(pn2, off, 64);
    // rigorous window for the split-f16 MFMA scan:
    // 2*delta <= 2*(~400*2^-24 + 3*2^-22)*||p||*||w|| + flush/round slack
    float eps = 6.0e-5f * sqrtf(pn2) * (*wmax) + 3e-5f;

    float marr[4];
    float AM = -__builtin_inff();
    #pragma unroll
    for (int i = 0; i < 4; ++i) {
        int cc = lane + 64 * i;
        marr[i] = (cc < NCHUNK) ? cmr[cc] : -__builtin_inff();
        AM = fmaxf(AM, marr[i]);
    }
    #pragma unroll
    for (int off = 1; off < 64; off <<= 1) AM = fmaxf(AM, __shfl_xor(AM, off, 64));
    double S = 0.0;
    #pragma unroll
    for (int i = 0; i < 4; ++i) {
        int cc = lane + 64 * i;
        if (cc < NCHUNK) S += (double)csr[cc];
    }
    #pragma unroll
    for (int off = 1; off < 64; off <<= 1) S += __shfl_xor(S, off, 64);

    // pass A: exact f64-recipe max over candidate chunks -> exact global max M
    float M = -__builtin_inff();
    #pragma unroll 1
    for (int i = 0; i < 4; ++i) {
        unsigned long long mask = __ballot(marr[i] >= AM - eps);
        while (mask) {
            int b = __ffsll(mask) - 1;
            mask &= mask - 1;
            int cc = i * 64 + b;
            #pragma unroll
            for (int q = 0; q < 2; ++q) {
                int v = cc * 128 + q * 64 + lane;
                double acc = 0.0;
                if (isf) {
                    const float* wv = (const float*)W2_raw + (long)v * H;
                    for (int k = 0; k < H; ++k) acc += (double)pr[k] * (double)wv[k];
                } else {
                    const unsigned short* wv = (const unsigned short*)W2_raw + (long)v * H;
                    for (int k = 0; k < H; ++k) acc += (double)pr[k] * (double)bf2f(wv[k]);
                }
                float l = __fadd_rn((float)acc, b2[v]);
                M = fmaxf(M, l);
            }
        }
    }
    #pragma unroll
    for (int off = 1; off < 64; off <<= 1) M = fmaxf(M, __shfl_xor(M, off, 64));

    float L = (float)(log(S) - (double)M);
    float negL = __fsub_rn(0.0f, L);

    // pass B: first v (ascending) whose f32 logprob equals the max logprob -L
    int best = INT_MAX;
    #pragma unroll 1
    for (int i = 0; i < 4 && best == INT_MAX; ++i) {
        unsigned long long mask = __ballot(marr[i] >= AM - eps);
        while (mask && best == INT_MAX) {
            int b = __ffsll(mask) - 1;
            mask &= mask - 1;
            int cc = i * 64 + b;
            int hit = INT_MAX;
            #pragma unroll
            for (int q = 0; q < 2; ++q) {
                int v = cc * 128 + q * 64 + lane;
                double acc = 0.0;
                if (isf) {
                    const float* wv = (const float*)W2_raw + (long)v * H;
                    for (int k = 0; k < H; ++k) acc += (double)pr[k] * (double)wv[k];
                } else {
                    const unsigned short* wv = (const unsigned short*)W2_raw + (long)v * H;
                    for (int k = 0; k < H; ++k) acc += (double)pr[k] * (double)bf2f(wv[k]);
                }
                float l  = __fadd_rn((float)acc, b2[v]);
                float lp = __fsub_rn(__fsub_rn(l, M), L);
                if (lp == negL && v < hit) hit = v;
            }
            #pragma unroll
            for (int off = 1; off < 64; off <<= 1) {
                int oh = __shfl_xor(hit, off, 64);
                hit = (oh < hit) ? oh : hit;
            }
            if (hit != INT_MAX) best = hit;
        }
    }
    int bi = (best == INT_MAX) ? 0 : best;

    int unfr = unf[r];
    float lp = negL;
    int itn = unfr ? bi : 0;
    int unfn = (unfr && itn != EOS) ? 1 : 0;
    if (lane == 0) { it[r] = itn; unf[r] = unfn; }
    if (lane < NS) {
        long ro = (long)r * NS + lane;
        out[ro * T_STEPS + t] = (float)itn;
        out[(long)BFULL * T_STEPS + ro * T_STEPS + t] = lp;
        out[2L * BFULL * T_STEPS + ro * T_STEPS + t] = unfr ? 1.0f : 0.0f;
    }
}

// ---------------------------------------------------------------- launch
extern "C" void kernel_launch(void* const* d_in, const int* in_sizes, int n_in,
                              void* d_out, int out_size, void* d_ws, size_t ws_size,
                              hipStream_t stream) {
    float* out = (float*)d_out;

    char* w = (char*)d_ws;
    float* fin[12];
    for (int i = 0; i < 12; ++i) {
        if (i == 1 || i == 10) { fin[i] = nullptr; continue; }   // embed/W2 read raw
        fin[i] = (float*)w;
        size_t bytes = ((size_t)in_sizes[i] * 4 + 15) & ~(size_t)15;
        w += bytes;
    }
    float*  h     = (float*) w; w += (size_t)B * H * 4;
    float*  c     = (float*) w; w += (size_t)B * H * 4;
    float*  gates = (float*) w; w += (size_t)B * 4 * H * 4;
    float*  p32   = (float*) w; w += (size_t)B * H * 4;
    float*  cm    = (float*) w; w += (size_t)B * NCHUNK * 4;
    float*  cs    = (float*) w; w += (size_t)B * NCHUNK * 4;
    float*  wn    = (float*) w; w += (size_t)V * 4;
    float*  wmax  = (float*) w; w += 16;
    int*    it    = (int*)   w; w += (size_t)B * 4;
    int*    unf   = (int*)   w; w += (size_t)B * 4;
    int*    flag  = (int*)   w; w += 16;
    unsigned short* ph = (unsigned short*)w; w += (size_t)B * H * 2;
    unsigned short* pl = (unsigned short*)w; w += (size_t)B * H * 2;
    unsigned short* wh = (unsigned short*)w; w += (size_t)V * H * 2;
    unsigned short* wl = (unsigned short*)w; w += (size_t)V * H * 2;

    k_detect<<<1, 64, 0, stream>>>((const unsigned short*)d_in[1], flag);
    for (int i = 0; i < 12; ++i) {
        if (i == 1 || i == 10) continue;
        int n = in_sizes[i];
        k_transcode<<<(n + 255) / 256, 256, 0, stream>>>(d_in[i], fin[i], n, flag);
    }
    k_wsplit<<<(V + 255) / 256, 256, 0, stream>>>(d_in[10], wh, wl, wn, flag);
    k_wmax<<<1, 256, 0, stream>>>(wn, wmax);

    const float* xf  = fin[0];
    const float* Wfc = fin[2];
    const float* bfc = fin[3];
    const float* Wih = fin[4];
    const float* bih = fin[5];
    const float* Whh = fin[6];
    const float* bhh = fin[7];
    const float* W1  = fin[8];
    const float* b1  = fin[9];
    const float* b2  = fin[11];

    k_init_state<<<(B + 255) / 256, 256, 0, stream>>>(it, unf);
    k_init_hc<<<B, 256, 0, stream>>>(xf, Wfc, bfc, h, c);
    for (int t = 0; t < T_STEPS; ++t) {
        k_gates<<<dim3(B / 64, 8), 256, 0, stream>>>(d_in[1], h, Wih, Whh, bih, bhh, it, gates, flag);
        k_cell_proj<<<B / 8, 256, 0, stream>>>(gates, h, c, W1, b1, p32, ph, pl);
        k_vscan_mfma<<<dim3(B / 256, NCHUNK), 256, 0, stream>>>(ph, pl, wh, wl, b2, cm, cs);
        k_final<<<B, 64, 0, stream>>>(cm, cs, p32, d_in[10], b2, wmax, it, unf, out, t, flag);
    }
}

// Round 2
// 2415.992 us; speedup vs baseline: 1.6392x; 1.2460x over previous
//
#include <hip/hip_runtime.h>
#include <math.h>
#include <limits.h>

#define H 128
#define V 32000
#define CD 256
#define T_STEPS 21
#define NS 5
#define SOS 1
#define EOS 2
#define B 1024          // unique rows; reference B=5120 is 5 identical copies of each
#define BFULL 5120
#define NCHUNK 250      // V / 128

typedef _Float16 f16;
typedef f16   half8   __attribute__((ext_vector_type(8)));
typedef float floatx4 __attribute__((ext_vector_type(4)));
typedef unsigned short ushort8v __attribute__((ext_vector_type(8)));

__device__ __forceinline__ float bf2f(unsigned short u) {
    return __uint_as_float(((unsigned)u) << 16);
}

// np-faithful f32 sigmoid/tanh: f64 interior, single f32 round per np op.
__device__ __forceinline__ float sig32(float x) {
    float t = (float)exp(-(double)x);
    float r = __fadd_rn(1.0f, t);
    return __fdiv_rn(1.0f, r);
}
__device__ __forceinline__ float tanh32(float x) { return (float)tanh((double)x); }

// ---------------------------------------------------------------- input dtype sniffer
__global__ void k_detect(const unsigned short* __restrict__ e, int* __restrict__ flag) {
    int i = threadIdx.x;
    unsigned short u = e[2 * i];
    int ex = (u >> 7) & 0xFF;
    bool wild = ((u & 0x7FFF) != 0) && (ex < 0x60 || ex > 0x8F);
    unsigned long long m = __ballot(wild);
    if (i == 0) *flag = (m != 0ull) ? 1 : 0;   // 1 = f32 inputs, 0 = bf16
}

// ---------------------------------------------------------------- transcode input -> f32
__global__ void k_transcode(const void* __restrict__ src, float* __restrict__ dst,
                            int n, const int* __restrict__ flag) {
    int i = blockIdx.x * blockDim.x + threadIdx.x;
    if (i >= n) return;
    if (*flag) dst[i] = ((const float*)src)[i];
    else       dst[i] = bf2f(((const unsigned short*)src)[i]);
}

// ---------------------------------------------------------------- W2: coalesced norm + scaled f16 hi/lo split (once per launch)
// Emits wh/wl in FRAGMENT-MAJOR order: f16 index = cb*16384 + kkg*1024 + row_local*8 + j
// where cb = vrow/128, row_local = vrow%128, kkg = k/8, j = k%8.
// This is exactly the LDS layout k_vscan_mfma consumes, so staging is a linear copy.
// Each thread handles 8 consecutive k of one vocab row (one 16B fragment chunk).
__global__ __launch_bounds__(256) void k_wsplit(
    const void* __restrict__ W2_raw, unsigned short* __restrict__ wh,
    unsigned short* __restrict__ wl, float* __restrict__ wn,
    const int* __restrict__ flag) {
    int t = blockIdx.x * 256 + threadIdx.x;       // t in [0, V*H/8)
    const bool isf = (*flag != 0);
    int vrow = t >> 4;                            // vocab row
    int kkg  = t & 15;                            // which 8-wide k group
    float v[8];
    if (isf) {
        float4 f0 = ((const float4*)W2_raw)[2 * t];
        float4 f1 = ((const float4*)W2_raw)[2 * t + 1];
        v[0] = f0.x; v[1] = f0.y; v[2] = f0.z; v[3] = f0.w;
        v[4] = f1.x; v[5] = f1.y; v[6] = f1.z; v[7] = f1.w;
    } else {
        ushort8v u = ((const ushort8v*)W2_raw)[t];
        #pragma unroll
        for (int i = 0; i < 8; ++i) v[i] = bf2f(u[i]);
    }
    float s = 0.f;
    half8 hv, lv;
    #pragma unroll
    for (int i = 0; i < 8; ++i) {
        s += v[i] * v[i];
        float ws = v[i] * 256.0f;
        f16 hh = (f16)ws;
        hv[i] = hh;
        lv[i] = (f16)(ws - (float)hh);
    }
    int cb = vrow >> 7, rloc = vrow & 127;
    long dst = (long)cb * 16384 + kkg * 1024 + rloc * 8;
    *(half8*)((f16*)wh + dst) = hv;
    *(half8*)((f16*)wl + dst) = lv;
    // row norm: 16 consecutive threads share a row
    #pragma unroll
    for (int off = 1; off < 16; off <<= 1) s += __shfl_xor(s, off, 64);
    if (kkg == 0) wn[vrow] = sqrtf(s);
}

// ---------------------------------------------------------------- global max ||w|| (once per launch)
__global__ __launch_bounds__(256) void k_wmax(const float* __restrict__ wn, float* __restrict__ wmax) {
    __shared__ float red[4];
    int tid = threadIdx.x;
    float m = 0.f;
    for (int i = tid; i < V; i += 256) m = fmaxf(m, wn[i]);
    #pragma unroll
    for (int off = 1; off < 64; off <<= 1) m = fmaxf(m, __shfl_xor(m, off, 64));
    if ((tid & 63) == 0) red[tid >> 6] = m;
    __syncthreads();
    if (tid == 0) *wmax = fmaxf(fmaxf(red[0], red[1]), fmaxf(red[2], red[3]));
}

// ---------------------------------------------------------------- init it/unf
__global__ void k_init_state(int* __restrict__ it, int* __restrict__ unf) {
    int i = blockIdx.x * blockDim.x + threadIdx.x;
    if (i < B) { it[i] = SOS; unf[i] = 1; }
}

// ---------------------------------------------------------------- hc = fl32(x @ W_fc.T) + b_fc
__global__ __launch_bounds__(256) void k_init_hc(
    const float* __restrict__ xf, const float* __restrict__ Wfc,
    const float* __restrict__ bfc, float* __restrict__ h, float* __restrict__ c) {
    __shared__ float xl[CD];
    int r = blockIdx.x;
    int j = threadIdx.x;
    xl[j] = xf[(long)r * CD + j];
    __syncthreads();
    const float4* w4 = (const float4*)(Wfc + (long)j * CD);
    double acc = 0.0;
    for (int k4 = 0; k4 < CD / 4; ++k4) {
        float4 w = w4[k4];
        int k = k4 * 4;
        acc += (double)xl[k]     * (double)w.x;
        acc += (double)xl[k + 1] * (double)w.y;
        acc += (double)xl[k + 2] * (double)w.z;
        acc += (double)xl[k + 3] * (double)w.w;
    }
    float hc = __fadd_rn((float)acc, bfc[j]);
    if (j < H) h[(long)r * H + j] = hc;
    else       c[(long)r * H + (j - H)] = hc;
}

// ---------------------------------------------------------------- gates (f32 np-faithful) — unchanged
__global__ __launch_bounds__(256) void k_gates(
    const void* __restrict__ embed_raw, const float* __restrict__ h,
    const float* __restrict__ Wih, const float* __restrict__ Whh,
    const float* __restrict__ bih, const float* __restrict__ bhh,
    const int* __restrict__ it, float* __restrict__ gates,
    const int* __restrict__ flag) {
    __shared__ float At[16][68];
    __shared__ float Wt[16][68];
    const bool isf = (*flag != 0);
    int tid = threadIdx.x;
    int tx = tid & 15, ty = tid >> 4;
    int rb = blockIdx.x * 64, gb = blockIdx.y * 64;
    int lr = tid >> 2;
    int lq = (tid & 3) * 4;
    int arow = rb + lr;
    int grow = gb + lr;
    int tok = it[arow];
    const float*          erow_f = (const float*)embed_raw + (long)tok * H;
    const unsigned short* erow_h = (const unsigned short*)embed_raw + (long)tok * H;
    const float* hrow = h + (long)arow * H;
    const float* wi   = Wih + (long)grow * H;
    const float* wh   = Whh + (long)grow * H;
    double acc1[4][4] = {};
    double acc2[4][4] = {};
    for (int k0 = 0; k0 < 2 * H; k0 += 16) {
        int k = k0 + lq;
        float v0, v1, v2, v3;
        if (k < H) {
            if (isf) {
                float4 f = *(const float4*)(erow_f + k);
                v0 = f.x; v1 = f.y; v2 = f.z; v3 = f.w;
            } else {
                ushort4 u = *(const ushort4*)(erow_h + k);
                v0 = bf2f(u.x); v1 = bf2f(u.y); v2 = bf2f(u.z); v3 = bf2f(u.w);
            }
        } else {
            float4 f = *(const float4*)(hrow + (k - H));
            v0 = f.x; v1 = f.y; v2 = f.z; v3 = f.w;
        }
        At[lq + 0][lr] = v0; At[lq + 1][lr] = v1; At[lq + 2][lr] = v2; At[lq + 3][lr] = v3;
        float4 g;
        if (k < H) g = *(const float4*)(wi + k);
        else       g = *(const float4*)(wh + (k - H));
        Wt[lq + 0][lr] = g.x; Wt[lq + 1][lr] = g.y; Wt[lq + 2][lr] = g.z; Wt[lq + 3][lr] = g.w;
        __syncthreads();
        if (k0 < H) {
            #pragma unroll
            for (int kk = 0; kk < 16; ++kk) {
                float a[4], w[4];
                #pragma unroll
                for (int i = 0; i < 4; ++i) a[i] = At[kk][ty * 4 + i];
                #pragma unroll
                for (int j = 0; j < 4; ++j) w[j] = Wt[kk][tx * 4 + j];
                #pragma unroll
                for (int i = 0; i < 4; ++i)
                    #pragma unroll
                    for (int j = 0; j < 4; ++j)
                        acc1[i][j] += (double)a[i] * (double)w[j];
            }
        } else {
            #pragma unroll
            for (int kk = 0; kk < 16; ++kk) {
                float a[4], w[4];
                #pragma unroll
                for (int i = 0; i < 4; ++i) a[i] = At[kk][ty * 4 + i];
                #pragma unroll
                for (int j = 0; j < 4; ++j) w[j] = Wt[kk][tx * 4 + j];
                #pragma unroll
                for (int i = 0; i < 4; ++i)
                    #pragma unroll
                    for (int j = 0; j < 4; ++j)
                        acc2[i][j] += (double)a[i] * (double)w[j];
            }
        }
        __syncthreads();
    }
    #pragma unroll
    for (int i = 0; i < 4; ++i) {
        long row = rb + ty * 4 + i;
        #pragma unroll
        for (int j = 0; j < 4; ++j) {
            int g = gb + tx * 4 + j;
            float t = __fadd_rn((float)acc1[i][j], bih[g]);
            t = __fadd_rn(t, (float)acc2[i][j]);
            t = __fadd_rn(t, bhh[g]);
            gates[row * (4 * H) + g] = t;
        }
    }
}

// ---------------------------------------------------------------- LSTM cell + p-projection (+ scaled f16 hi/lo split of p)
__global__ __launch_bounds__(256) void k_cell_proj(
    const float* __restrict__ gates, float* __restrict__ h, float* __restrict__ c,
    const float* __restrict__ W1, const float* __restrict__ b1,
    float* __restrict__ p32, unsigned short* __restrict__ ph,
    unsigned short* __restrict__ pl) {
    __shared__ float hl[8][132];
    int tid = threadIdx.x;
    int rb = blockIdx.x * 8;
    #pragma unroll
    for (int i = 0; i < 4; ++i) {
        int lin = tid + i * 256;
        int lr = lin >> 7, j = lin & 127;
        long row = rb + lr;
        const float* g = gates + row * 512;
        float gi = g[j], gf = g[j + 128], gg = g[j + 256], go = g[j + 384];
        float cv = c[row * 128 + j];
        float si = sig32(gi);
        float sf = sig32(gf);
        float so = sig32(go);
        float tg = tanh32(gg);
        float cn = __fadd_rn(__fmul_rn(sf, cv), __fmul_rn(si, tg));
        float hn = __fmul_rn(so, tanh32(cn));
        c[row * 128 + j] = cn;
        h[row * 128 + j] = hn;
        hl[lr][j] = hn;
    }
    __syncthreads();
    int j = tid & 127;
    int rbase = (tid >> 7) * 4;
    const float4* w4 = (const float4*)(W1 + (long)j * H);
    double acc[4] = {};
    for (int k4 = 0; k4 < H / 4; ++k4) {
        float4 w = w4[k4];
        int k = k4 * 4;
        #pragma unroll
        for (int rr = 0; rr < 4; ++rr) {
            acc[rr] += (double)hl[rbase + rr][k]     * (double)w.x;
            acc[rr] += (double)hl[rbase + rr][k + 1] * (double)w.y;
            acc[rr] += (double)hl[rbase + rr][k + 2] * (double)w.z;
            acc[rr] += (double)hl[rbase + rr][k + 3] * (double)w.w;
        }
    }
    #pragma unroll
    for (int rr = 0; rr < 4; ++rr) {
        long row = rb + rbase + rr;
        float pv = __fadd_rn((float)acc[rr], b1[j]);
        p32[row * H + j] = pv;
        float ps = pv * 256.0f;
        f16 hh = (f16)ps;
        f16 ll = (f16)(ps - (float)hh);
        ((f16*)ph)[row * H + j] = hh;
        ((f16*)pl)[row * H + j] = ll;
    }
}

// ---------------------------------------------------------------- vocab scan via split-f16 MFMA, LDS-staged B:
// logit = 2^-16 * (p_hi.W_hi + p_hi.W_lo + p_lo.W_hi) + b2, f32 MFMA accum.
// B tile (128 cols x K=128, hi+lo = 64KB) staged once per block into LDS
// (linear copy — wh/wl are pre-arranged fragment-major by k_wsplit), shared
// by all 4 waves; MFMA inner loop reads B via ds_read_b128 (optimal bank
// coverage: row stride 16B -> starts 0,4,..,28, 2 dwords/bank).
// XCD-grouped swizzle: the 4 row-blocks sharing a B tile get the same bid%8.
__global__ __launch_bounds__(256, 2) void k_vscan_mfma(
    const unsigned short* __restrict__ ph_, const unsigned short* __restrict__ pl_,
    const unsigned short* __restrict__ whf_, const unsigned short* __restrict__ wlf_,
    const float* __restrict__ b2, float* __restrict__ cm, float* __restrict__ cs) {
    __shared__ f16 Bsh[16384];   // 32 KB
    __shared__ f16 Bsl[16384];   // 32 KB
    const f16* ph  = (const f16*)ph_;
    const f16* pl  = (const f16*)pl_;
    const f16* whf = (const f16*)whf_;
    const f16* wlf = (const f16*)wlf_;
    int tid  = threadIdx.x;
    int lane = tid & 63, wid = tid >> 6;
    int tx = lane & 15, kg = lane >> 4;

    // bid = hi*32 + rb*8 + xcd  ->  cb = hi*8 + xcd  (same cb -> same bid%8 -> same XCD)
    int bid = blockIdx.x;
    int xcd = bid & 7, rb = (bid >> 3) & 3, hi = bid >> 5;
    int cb = hi * 8 + xcd;
    if (cb >= NCHUNK) return;
    int rbw = rb * 256 + wid * 64;
    int vb  = cb * 128;

    // stage B tile: linear 32KB copy per array (global fragment-major == LDS layout)
    {
        const f16* sh = whf + (long)cb * 16384;
        const f16* sl = wlf + (long)cb * 16384;
        #pragma unroll
        for (int i = 0; i < 8; ++i) {
            int g = tid + 256 * i;           // 16B chunk id, 0..2047
            *(half8*)(Bsh + g * 8) = *(const half8*)(sh + g * 8);
            *(half8*)(Bsl + g * 8) = *(const half8*)(sl + g * 8);
        }
    }
    __syncthreads();

    floatx4 acc[4][8];
    #pragma unroll
    for (int m = 0; m < 4; ++m)
        #pragma unroll
        for (int n = 0; n < 8; ++n)
            acc[m][n] = (floatx4){0.f, 0.f, 0.f, 0.f};

    int aoffs[4];
    #pragma unroll
    for (int m = 0; m < 4; ++m) aoffs[m] = (rbw + m * 16 + tx) * H + kg * 8;

    #pragma unroll
    for (int kk = 0; kk < 4; ++kk) {
        half8 Ah[4], Al[4];
        #pragma unroll
        for (int m = 0; m < 4; ++m) {
            Ah[m] = *(const half8*)(ph + aoffs[m] + kk * 32);
            Al[m] = *(const half8*)(pl + aoffs[m] + kk * 32);
        }
        int bbase = (kk * 4 + kg) * 1024 + tx * 8;
        #pragma unroll
        for (int n = 0; n < 8; ++n) {
            half8 Bh = *(const half8*)(Bsh + bbase + n * 128);
            half8 Bl = *(const half8*)(Bsl + bbase + n * 128);
            #pragma unroll
            for (int m = 0; m < 4; ++m)
                acc[m][n] = __builtin_amdgcn_mfma_f32_16x16x32_f16(Ah[m], Bh, acc[m][n], 0, 0, 0);
            #pragma unroll
            for (int m = 0; m < 4; ++m)
                acc[m][n] = __builtin_amdgcn_mfma_f32_16x16x32_f16(Ah[m], Bl, acc[m][n], 0, 0, 0);
            #pragma unroll
            for (int m = 0; m < 4; ++m)
                acc[m][n] = __builtin_amdgcn_mfma_f32_16x16x32_f16(Al[m], Bh, acc[m][n], 0, 0, 0);
        }
    }

    // epilogue: descale (exact 2^-16), bias, per-(row,chunk) max + expf-sum.
    // C/D layout: col = lane&15 (tx), row = kg*4 + reg.
    const float S2 = 1.0f / 65536.0f;
    float bb[8];
    #pragma unroll
    for (int n = 0; n < 8; ++n) bb[n] = b2[vb + n * 16 + tx];
    #pragma unroll
    for (int m = 0; m < 4; ++m) {
        #pragma unroll
        for (int r = 0; r < 4; ++r) {
            float mxr = -__builtin_inff();
            float sr = 0.f;
            #pragma unroll
            for (int n = 0; n < 8; ++n) {
                float l = acc[m][n][r] * S2 + bb[n];
                mxr = fmaxf(mxr, l);
                sr += __expf(l);
            }
            #pragma unroll
            for (int off = 1; off < 16; off <<= 1) {
                mxr = fmaxf(mxr, __shfl_xor(mxr, off, 64));
                sr += __shfl_xor(sr, off, 64);
            }
            if (tx == 0) {
                long row = rbw + m * 16 + kg * 4 + r;
                cm[row * NCHUNK + cb] = mxr;
                cs[row * NCHUNK + cb] = sr;
            }
        }
    }
}

// ---------------------------------------------------------------- finalize: norm-bounded candidate set, exact f64 rescue
__global__ __launch_bounds__(64) void k_final(
    const float* __restrict__ cm, const float* __restrict__ cs,
    const float* __restrict__ p32, const void* __restrict__ W2_raw,
    const float* __restrict__ b2, const float* __restrict__ wmax,
    int* __restrict__ it, int* __restrict__ unf,
    float* __restrict__ out, int t, const int* __restrict__ flag) {
    const bool isf = (*flag != 0);
    int r = blockIdx.x;
    int lane = threadIdx.x;
    const float* cmr = cm + (long)r * NCHUNK;
    const float* csr = cs + (long)r * NCHUNK;
    const float* pr = p32 + (long)r * H;

    // ||p||
    float pa = pr[lane], pb = pr[lane + 64];
    float pn2 = pa * pa + pb * pb;
    #pragma unroll
    for (int off = 1; off < 64; off <<= 1) pn2 += __shfl_xor(pn2, off, 64);
    // rigorous window for the split-f16 MFMA scan:
    // 2*delta <= 2*(~400*2^-24 + 3*2^-22)*||p||*||w|| + flush/round slack
    float eps = 6.0e-5f * sqrtf(pn2) * (*wmax) + 3e-5f;

    float marr[4];
    float AM = -__builtin_inff();
    #pragma unroll
    for (int i = 0; i < 4; ++i) {
        int cc = lane + 64 * i;
        marr[i] = (cc < NCHUNK) ? cmr[cc] : -__builtin_inff();
        AM = fmaxf(AM, marr[i]);
    }
    #pragma unroll
    for (int off = 1; off < 64; off <<= 1) AM = fmaxf(AM, __shfl_xor(AM, off, 64));
    double S = 0.0;
    #pragma unroll
    for (int i = 0; i < 4; ++i) {
        int cc = lane + 64 * i;
        if (cc < NCHUNK) S += (double)csr[cc];
    }
    #pragma unroll
    for (int off = 1; off < 64; off <<= 1) S += __shfl_xor(S, off, 64);

    // pass A: exact f64-recipe max over candidate chunks -> exact global max M
    float M = -__builtin_inff();
    #pragma unroll 1
    for (int i = 0; i < 4; ++i) {
        unsigned long long mask = __ballot(marr[i] >= AM - eps);
        while (mask) {
            int b = __ffsll(mask) - 1;
            mask &= mask - 1;
            int cc = i * 64 + b;
            #pragma unroll
            for (int q = 0; q < 2; ++q) {
                int v = cc * 128 + q * 64 + lane;
                double acc = 0.0;
                if (isf) {
                    const float* wv = (const float*)W2_raw + (long)v * H;
                    for (int k = 0; k < H; ++k) acc += (double)pr[k] * (double)wv[k];
                } else {
                    const unsigned short* wv = (const unsigned short*)W2_raw + (long)v * H;
                    for (int k = 0; k < H; ++k) acc += (double)pr[k] * (double)bf2f(wv[k]);
                }
                float l = __fadd_rn((float)acc, b2[v]);
                M = fmaxf(M, l);
            }
        }
    }
    #pragma unroll
    for (int off = 1; off < 64; off <<= 1) M = fmaxf(M, __shfl_xor(M, off, 64));

    float L = (float)(log(S) - (double)M);
    float negL = __fsub_rn(0.0f, L);

    // pass B: first v (ascending) whose f32 logprob equals the max logprob -L
    int best = INT_MAX;
    #pragma unroll 1
    for (int i = 0; i < 4 && best == INT_MAX; ++i) {
        unsigned long long mask = __ballot(marr[i] >= AM - eps);
        while (mask && best == INT_MAX) {
            int b = __ffsll(mask) - 1;
            mask &= mask - 1;
            int cc = i * 64 + b;
            int hit = INT_MAX;
            #pragma unroll
            for (int q = 0; q < 2; ++q) {
                int v = cc * 128 + q * 64 + lane;
                double acc = 0.0;
                if (isf) {
                    const float* wv = (const float*)W2_raw + (long)v * H;
                    for (int k = 0; k < H; ++k) acc += (double)pr[k] * (double)wv[k];
                } else {
                    const unsigned short* wv = (const unsigned short*)W2_raw + (long)v * H;
                    for (int k = 0; k < H; ++k) acc += (double)pr[k] * (double)bf2f(wv[k]);
                }
                float l  = __fadd_rn((float)acc, b2[v]);
                float lp = __fsub_rn(__fsub_rn(l, M), L);
                if (lp == negL && v < hit) hit = v;
            }
            #pragma unroll
            for (int off = 1; off < 64; off <<= 1) {
                int oh = __shfl_xor(hit, off, 64);
                hit = (oh < hit) ? oh : hit;
            }
            if (hit != INT_MAX) best = hit;
        }
    }
    int bi = (best == INT_MAX) ? 0 : best;

    int unfr = unf[r];
    float lp = negL;
    int itn = unfr ? bi : 0;
    int unfn = (unfr && itn != EOS) ? 1 : 0;
    if (lane == 0) { it[r] = itn; unf[r] = unfn; }
    if (lane < NS) {
        long ro = (long)r * NS + lane;
        out[ro * T_STEPS + t] = (float)itn;
        out[(long)BFULL * T_STEPS + ro * T_STEPS + t] = lp;
        out[2L * BFULL * T_STEPS + ro * T_STEPS + t] = unfr ? 1.0f : 0.0f;
    }
}

// ---------------------------------------------------------------- launch
extern "C" void kernel_launch(void* const* d_in, const int* in_sizes, int n_in,
                              void* d_out, int out_size, void* d_ws, size_t ws_size,
                              hipStream_t stream) {
    float* out = (float*)d_out;

    char* w = (char*)d_ws;
    float* fin[12];
    for (int i = 0; i < 12; ++i) {
        if (i == 1 || i == 10) { fin[i] = nullptr; continue; }   // embed/W2 read raw
        fin[i] = (float*)w;
        size_t bytes = ((size_t)in_sizes[i] * 4 + 15) & ~(size_t)15;
        w += bytes;
    }
    float*  h     = (float*) w; w += (size_t)B * H * 4;
    float*  c     = (float*) w; w += (size_t)B * H * 4;
    float*  gates = (float*) w; w += (size_t)B * 4 * H * 4;
    float*  p32   = (float*) w; w += (size_t)B * H * 4;
    float*  cm    = (float*) w; w += (size_t)B * NCHUNK * 4;
    float*  cs    = (float*) w; w += (size_t)B * NCHUNK * 4;
    float*  wn    = (float*) w; w += (size_t)V * 4;
    float*  wmax  = (float*) w; w += 16;
    int*    it    = (int*)   w; w += (size_t)B * 4;
    int*    unf   = (int*)   w; w += (size_t)B * 4;
    int*    flag  = (int*)   w; w += 16;
    unsigned short* ph = (unsigned short*)w; w += (size_t)B * H * 2;
    unsigned short* pl = (unsigned short*)w; w += (size_t)B * H * 2;
    unsigned short* wh = (unsigned short*)w; w += (size_t)V * H * 2;
    unsigned short* wl = (unsigned short*)w; w += (size_t)V * H * 2;

    k_detect<<<1, 64, 0, stream>>>((const unsigned short*)d_in[1], flag);
    for (int i = 0; i < 12; ++i) {
        if (i == 1 || i == 10) continue;
        int n = in_sizes[i];
        k_transcode<<<(n + 255) / 256, 256, 0, stream>>>(d_in[i], fin[i], n, flag);
    }
    k_wsplit<<<(V * H / 8 + 255) / 256, 256, 0, stream>>>(d_in[10], wh, wl, wn, flag);
    k_wmax<<<1, 256, 0, stream>>>(wn, wmax);

    const float* xf  = fin[0];
    const float* Wfc = fin[2];
    const float* bfc = fin[3];
    const float* Wih = fin[4];
    const float* bih = fin[5];
    const float* Whh = fin[6];
    const float* bhh = fin[7];
    const float* W1  = fin[8];
    const float* b1  = fin[9];
    const float* b2  = fin[11];

    k_init_state<<<(B + 255) / 256, 256, 0, stream>>>(it, unf);
    k_init_hc<<<B, 256, 0, stream>>>(xf, Wfc, bfc, h, c);
    for (int t = 0; t < T_STEPS; ++t) {
        k_gates<<<dim3(B / 64, 8), 256, 0, stream>>>(d_in[1], h, Wih, Whh, bih, bhh, it, gates, flag);
        k_cell_proj<<<B / 8, 256, 0, stream>>>(gates, h, c, W1, b1, p32, ph, pl);
        k_vscan_mfma<<<1024, 256, 0, stream>>>(ph, pl, wh, wl, b2, cm, cs);
        k_final<<<B, 64, 0, stream>>>(cm, cs, p32, d_in[10], b2, wmax, it, unf, out, t, flag);
    }
}